// Round 7
// baseline (136.102 us; speedup 1.0000x reference)
//
#include <hip/hip_runtime.h>
#include <math.h>
#include <float.h>

#define BN 2
#define NP 1024
#define NC 81
#define NCLS 80           // NC-1 foreground classes
#define ND 100
#define NSLOT 64          // fixed survivor slots per (image,class)
#define CAP2 512          // general-path candidate cap
#define CAPT 512          // tail compacted-superset cap
#define NBIN 4096
#define CHROWS 128
#define NCHUNK 8          // 1024 / 128
#define SCORE_T 0.05f
#define NMS_T 0.5f
#define BBOX_CLIP 4.135166556742356f   // log(1000/16)
#define DONE_TAG 0x5A5A5A5A            // != 0xAAAAAAAA ws poison

typedef unsigned long long ull;

// Decode one box, identical op order everywhere so results are bit-equal across uses.
__device__ __forceinline__ void decode_box(
    const float* __restrict__ props, const float* __restrict__ regress,
    int b, int n, int c, float& x1, float& y1, float& x2, float& y2)
{
    const float* pr = props + ((size_t)b * NP + n) * 4;
    float p0 = pr[0], p1 = pr[1], p2 = pr[2], p3 = pr[3];
    float w  = p2 - p0 + 1.0f, h = p3 - p1 + 1.0f;
    float cx = p0 + 0.5f * w,  cy = p1 + 0.5f * h;
    const float* rl = regress + (((size_t)b * NP + n) * NC + c) * 4;
    float dx = rl[0] / 10.0f, dy = rl[1] / 10.0f;
    float dw = fminf(rl[2] / 5.0f, BBOX_CLIP);
    float dh = fminf(rl[3] / 5.0f, BBOX_CLIP);
    float pcx = dx * w + cx, pcy = dy * h + cy;
    float pw  = expf(dw) * w, ph = expf(dh) * h;
    x1 = pcx - 0.5f * pw; y1 = pcy - 0.5f * ph;
    x2 = pcx + 0.5f * pw - 1.0f; y2 = pcy + 0.5f * ph - 1.0f;
    x1 = fminf(fmaxf(x1, 0.f), 1023.f);
    y1 = fminf(fmaxf(y1, 0.f), 1023.f);
    x2 = fminf(fmaxf(x2, 0.f), 1023.f);
    y2 = fminf(fmaxf(y2, 0.f), 1023.f);
}

__device__ __forceinline__ void emit_slot(
    float* __restrict__ out, const float* __restrict__ props,
    const float* __restrict__ regress, int b, int d, ull key)
{
    float score = __uint_as_float((unsigned int)(key >> 32));
    float* ob = out + ((size_t)b * ND + d) * 4;
    float* os = out + (size_t)BN * ND * 4 + b * ND + d;
    float* ol = out + (size_t)BN * ND * 5 + b * ND + d;
    if (score > 0.f) {
        unsigned int f = 0xFFFFFFFFu - (unsigned int)(key & 0xFFFFFFFFu);
        int cls = f / NP, n = f % NP;
        float x1, y1, x2, y2;
        decode_box(props, regress, b, n, cls + 1, x1, y1, x2, y2);
        ob[0] = x1; ob[1] = y1; ob[2] = x2; ob[3] = y2;
        *os = score;
        *ol = (float)(cls + 1);
    } else {
        ob[0] = 0.f; ob[1] = 0.f; ob[2] = 0.f; ob[3] = 0.f;
        *os = 0.f;
        *ol = -1.f;
    }
}

__device__ __forceinline__ void bitonic_desc(ull* a, int len, int tid, int nthr)
{
    for (int k = 2; k <= len; k <<= 1) {
        for (int j = k >> 1; j > 0; j >>= 1) {
            for (int i = tid; i < len; i += nthr) {
                int ixj = i ^ j;
                if (ixj > i) {
                    bool desc = ((i & k) == 0);
                    ull x = a[i], y = a[ixj];
                    if (desc ? (x < y) : (x > y)) { a[i] = y; a[ixj] = x; }
                }
            }
            __syncthreads();
        }
    }
}

// ---------------- Single fused kernel: softmax + NMS + spin-tail top-100 ----------------
__global__ __launch_bounds__(256) void roihead_kernel(
    const float* __restrict__ logits, const float* __restrict__ regress,
    const float* __restrict__ props, int* __restrict__ flags,
    ull* __restrict__ g_key, float* __restrict__ out)
{
    const int tid  = threadIdx.x;
    const int l    = tid & 63;
    const int wave = tid >> 6;
    const int idx  = blockIdx.x;
    const int b    = idx / NCLS;
    const int cls  = idx % NCLS;
    const int c    = cls + 1;

    __shared__ union {
        float4 stage4[CHROWS * NC / 4];           // 41,472 B logits chunk
        struct {                                  // general NMS path: 16 KB
            ull   key[CAP2];
            float x1[CAP2], y1[CAP2], x2[CAP2], y2[CAP2], area[CAP2];
            int   keep[CAP2];
        } a;
        struct {                                  // tail phase: 20 KB
            int hist[NBIN];
            ull cbuf[CAPT];
        } t;
    } sm;
    __shared__ float sp[NP];                      // this class's 1024 probs (4 KB)
    __shared__ int s_cnt, s_app, s_bstar, s_cnt2;

    // ---- phase 0: per-block softmax (bit-identical sequential order) ----
    const float4* lg4 = (const float4*)(logits + (size_t)b * NP * NC);
    for (int ch = 0; ch < NCHUNK; ++ch) {
        const float4* src = lg4 + ch * (CHROWS * NC / 4);
        for (int i = tid; i < CHROWS * NC / 4; i += 256) sm.stage4[i] = src[i];
        __syncthreads();
        if (tid < CHROWS) {
            const float* row = (const float*)sm.stage4 + tid * NC;
            float m = -FLT_MAX;
            for (int i = 0; i < NC; ++i) m = fmaxf(m, row[i]);
            float s = 0.f;
            for (int i = 0; i < NC; ++i) s += expf(row[i] - m);
            sp[ch * CHROWS + tid] = expf(row[c] - m) / s;
        }
        __syncthreads();
    }

    // ---- phase 1: scan & compact candidates (keys carry ~n for tie-break) ----
    if (tid == 0) { s_cnt = 0; s_app = 0; }
    __syncthreads();
    float4 v = ((const float4*)sp)[tid];
    #pragma unroll
    for (int q = 0; q < 4; ++q) {
        float p = (&v.x)[q];
        if (p > SCORE_T) {
            int k = atomicAdd(&s_cnt, 1);
            if (k < CAP2) {
                unsigned n = (unsigned)(tid * 4 + q);
                sm.a.key[k] = ((ull)__float_as_uint(p) << 32)
                            | (ull)(0xFFFFFFFFu - n);
            }
        }
    }
    __syncthreads();
    int M = s_cnt; if (M > CAP2) M = CAP2;
    ull* g_slot = g_key + (size_t)idx * NSLOT;

    // ---- phase 2: NMS ----
    if (M > 64) {
        // general path (rare): LDS bitonic + barriered NMS, 256 threads
        int Mp = 128; while (Mp < M) Mp <<= 1;
        for (int i = M + tid; i < Mp; i += 256) sm.a.key[i] = 0ull;
        __syncthreads();
        bitonic_desc(sm.a.key, Mp, tid, 256);
        for (int i = tid; i < M; i += 256) {
            int n = (int)(0xFFFFFFFFu - (unsigned)(sm.a.key[i] & 0xFFFFFFFFu));
            float x1, y1, x2, y2;
            decode_box(props, regress, b, n, c, x1, y1, x2, y2);
            sm.a.x1[i] = x1; sm.a.y1[i] = y1; sm.a.x2[i] = x2; sm.a.y2[i] = y2;
            sm.a.area[i] = (x2 - x1 + 1.f) * (y2 - y1 + 1.f);
            sm.a.keep[i] = 1;
        }
        __syncthreads();
        for (int i = 0; i < M; ++i) {
            if (sm.a.keep[i]) {
                float x1i = sm.a.x1[i], y1i = sm.a.y1[i];
                float x2i = sm.a.x2[i], y2i = sm.a.y2[i], ai = sm.a.area[i];
                for (int j = i + 1 + tid; j < M; j += 256) {
                    float lx = fmaxf(x1i, sm.a.x1[j]);
                    float ly = fmaxf(y1i, sm.a.y1[j]);
                    float rx = fminf(x2i, sm.a.x2[j]);
                    float ry = fminf(y2i, sm.a.y2[j]);
                    float wd = fmaxf(rx - lx + 1.f, 0.f);
                    float ht = fmaxf(ry - ly + 1.f, 0.f);
                    float inter = wd * ht;
                    float iou = inter / (ai + sm.a.area[j] - inter);
                    if (iou > NMS_T) sm.a.keep[j] = 0;
                }
            }
            __syncthreads();
        }
        for (int i = tid; i < M; i += 256) {
            if (sm.a.keep[i]) {
                int pos = atomicAdd(&s_app, 1);
                if (pos < NSLOT) {
                    ull key = sm.a.key[i];
                    unsigned n = 0xFFFFFFFFu - (unsigned)(key & 0xFFFFFFFFu);
                    unsigned f = (unsigned)cls * NP + n;
                    g_slot[pos] = (key & 0xFFFFFFFF00000000ull)
                                | (ull)(0xFFFFFFFFu - f);
                }
            }
        }
        __syncthreads();
        int st = s_app; if (st > NSLOT) st = NSLOT;
        for (int i = st + tid; i < NSLOT; i += 256) g_slot[i] = 0ull;
    } else {
        // fast path: whole NMS in wave-0 registers (proven R6 network)
        if (wave == 0) {
            ull key = (l < M) ? sm.a.key[l] : 0ull;
            #pragma unroll
            for (int k = 2; k <= 64; k <<= 1) {
                #pragma unroll
                for (int j = k >> 1; j > 0; j >>= 1) {
                    ull p = __shfl_xor(key, j, 64);
                    bool lower = (l & j) == 0;
                    bool up    = (l & k) != 0;
                    ull mn = key < p ? key : p;
                    ull mx = key < p ? p : key;
                    key = (lower == up) ? mn : mx;
                }
            }
            float x1 = 0.f, y1 = 0.f, x2 = 0.f, y2 = 0.f, ar = 0.f;
            if (l < M) {
                int n = (int)(0xFFFFFFFFu - (unsigned)(key & 0xFFFFFFFFu));
                decode_box(props, regress, b, n, c, x1, y1, x2, y2);
                ar = (x2 - x1 + 1.f) * (y2 - y1 + 1.f);
            }
            ull keep = (M >= 64) ? ~0ull : ((1ull << M) - 1ull);
            for (int i = 0; i < M; ++i) {
                if ((keep >> i) & 1ull) {
                    float xi1 = __shfl(x1, i, 64), yi1 = __shfl(y1, i, 64);
                    float xi2 = __shfl(x2, i, 64), yi2 = __shfl(y2, i, 64);
                    float ari = __shfl(ar, i, 64);
                    float lx = fmaxf(xi1, x1), ly = fmaxf(yi1, y1);
                    float rx = fminf(xi2, x2), ry = fminf(yi2, y2);
                    float wd = fmaxf(rx - lx + 1.f, 0.f);
                    float ht = fmaxf(ry - ly + 1.f, 0.f);
                    float inter = wd * ht;
                    float iou = inter / (ari + ar - inter);
                    ull sup = __ballot(iou > NMS_T && l > i);
                    keep &= ~sup;
                }
            }
            ull vout = 0ull;
            if ((keep >> l) & 1ull) {
                unsigned n = 0xFFFFFFFFu - (unsigned)(key & 0xFFFFFFFFu);
                unsigned f = (unsigned)cls * NP + n;
                vout = (key & 0xFFFFFFFF00000000ull) | (ull)(0xFFFFFFFFu - f);
            }
            g_slot[l] = vout;    // all 64 slots written (zeros where no survivor)
        }
    }

    // ---- release: slots visible, then tag this class done ----
    __syncthreads();
    __threadfence();
    if (tid == 0) atomicExch(&flags[idx], DONE_TAG);
    if (cls != 0) return;

    // ---- tail (cls==0 block per image): spin on 80 flags, then top-100 ----
    if (tid < NCLS) {
        int* fp = flags + b * NCLS + tid;
        while (atomicAdd(fp, 0) != DONE_TAG) { }
    }
    __syncthreads();
    __threadfence();                               // acquire: invalidate stale L1/L2

    const int K = NCLS * NSLOT;                    // 5120 fixed slots
    const ull* keys = g_key + (size_t)b * NCLS * NSLOT;

    for (int i = tid; i < NBIN; i += 256) sm.t.hist[i] = 0;
    if (tid == 0) s_cnt2 = 0;
    __syncthreads();
    for (int i = tid; i < K; i += 256) {
        ull key = keys[i];
        if (key) atomicAdd(&sm.t.hist[(int)(key >> 52)], 1);
    }
    __syncthreads();

    // boundary bin b*: wave 0, suffix scan over 4096 bins (64 groups x 64)
    if (tid < 64) {
        int gs = 0;
        for (int q = 0; q < 64; ++q) gs += sm.t.hist[l * 64 + q];
        int pre = gs;
        for (int off = 1; off < 64; off <<= 1) {
            int vv = __shfl_up(pre, off, 64);
            if (l >= off) pre += vv;
        }
        int total = __shfl(pre, 63, 64);
        int S = total - pre + gs;
        ull ball = __ballot(S >= ND);
        int gstar = ball ? (63 - __clzll((long long)ball)) : 0;
        int Sg = __shfl(S, gstar, 64);
        int Gg = __shfl(gs, gstar, 64);
        int A  = Sg - Gg;
        int h  = sm.t.hist[gstar * 64 + l];
        int pre2 = h;
        for (int off = 1; off < 64; off <<= 1) {
            int vv = __shfl_up(pre2, off, 64);
            if (l >= off) pre2 += vv;
        }
        int T = Gg - pre2 + h;
        ull ball2 = __ballot(A + T >= ND);
        int binin = ball2 ? (63 - __clzll((long long)ball2)) : 0;
        if (l == 0) s_bstar = gstar * 64 + binin;
    }
    __syncthreads();
    const int bstar = s_bstar;

    for (int i = tid; i < K; i += 256) {
        ull key = keys[i];
        if (key && (int)(key >> 52) >= bstar) {
            int p = atomicAdd(&s_cnt2, 1);
            if (p < CAPT) sm.t.cbuf[p] = key;
        }
    }
    __syncthreads();
    const int Tt = s_cnt2;

    if (Tt <= 256) {
        // zero-barrier register bitonic: 256 elems = 64 lanes x 4 regs, e = r*64 + l
        if (wave == 0) {
            ull key4[4];
            #pragma unroll
            for (int r = 0; r < 4; ++r) {
                int e = r * 64 + l;
                key4[r] = (e < Tt) ? sm.t.cbuf[e] : 0ull;
            }
            #pragma unroll
            for (int k = 2; k <= 256; k <<= 1) {
                #pragma unroll
                for (int j = k >> 1; j > 0; j >>= 1) {
                    if (j >= 64) {
                        int d = j >> 6;                       // 1 or 2: in-thread pairs
                        #pragma unroll
                        for (int r = 0; r < 4; ++r) {
                            if ((r & d) == 0) {
                                int e = r * 64 + l;
                                bool desc = ((e & k) == 0);
                                ull aa = key4[r], bb = key4[r | d];
                                if (desc ? (aa < bb) : (aa > bb)) {
                                    key4[r] = bb; key4[r | d] = aa;
                                }
                            }
                        }
                    } else {
                        #pragma unroll
                        for (int r = 0; r < 4; ++r) {
                            ull p = __shfl_xor(key4[r], j, 64);
                            int e = r * 64 + l;
                            bool desc = ((e & k) == 0);
                            bool low  = ((l & j) == 0);
                            ull mn = key4[r] < p ? key4[r] : p;
                            ull mx = key4[r] < p ? p : key4[r];
                            key4[r] = (low == desc) ? mx : mn;
                        }
                    }
                }
            }
            emit_slot(out, props, regress, b, l, key4[0]);
            if (l < ND - 64) emit_slot(out, props, regress, b, 64 + l, key4[1]);
        }
    } else if (Tt <= CAPT) {
        int Tp = 512;
        for (int i = Tt + tid; i < Tp; i += 256) sm.t.cbuf[i] = 0ull;
        __syncthreads();
        bitonic_desc(sm.t.cbuf, Tp, tid, 256);
        for (int d = tid; d < ND; d += 256)
            emit_slot(out, props, regress, b, d, sm.t.cbuf[d]);
    } else {
        // fallback (statistically unreachable): ND destructive argmax rounds
        ull* rk = sm.a.key;
        int* rp = sm.a.keep;
        ull* wkeys = g_key + (size_t)b * NCLS * NSLOT;
        for (int d = 0; d < ND; ++d) {
            ull bk = 0ull; int bp = -1;
            for (int t = tid; t < K; t += 256) {
                ull k2 = wkeys[t];
                if (k2 > bk) { bk = k2; bp = t; }
            }
            rk[tid] = bk; rp[tid] = bp;
            __syncthreads();
            for (int off = 128; off > 0; off >>= 1) {
                if (tid < off && rk[tid + off] > rk[tid]) {
                    rk[tid] = rk[tid + off]; rp[tid] = rp[tid + off];
                }
                __syncthreads();
            }
            if (tid == 0) {
                emit_slot(out, props, regress, b, d, rk[0]);
                if (rp[0] >= 0) wkeys[rp[0]] = 0ull;
            }
            __syncthreads();
        }
    }
}

extern "C" void kernel_launch(void* const* d_in, const int* in_sizes, int n_in,
                              void* d_out, int out_size, void* d_ws, size_t ws_size,
                              hipStream_t stream) {
    const float* logits  = (const float*)d_in[0];   // [B, N, C]
    const float* regress = (const float*)d_in[1];   // [B, N, C*4]
    const float* props   = (const float*)d_in[2];   // [B, N, 4]
    float* out = (float*)d_out;                     // boxes(800) | scores(200) | labels(200)

    // Workspace layout (no zero-init needed anywhere):
    //   [0    , 640  )  flags : BN*NCLS ints, poison 0xAAAAAAAA != DONE_TAG
    //   [1024 , 82944)  g_key : BN*NCLS*NSLOT u64 fixed survivor slots (80 KB)
    char* ws = (char*)d_ws;
    int* flags = (int*)(ws);
    ull* g_key = (ull*)(ws + 1024);

    hipLaunchKernelGGL(roihead_kernel, dim3(BN * NCLS), dim3(256), 0, stream,
                       logits, regress, props, flags, g_key, out);
}

// Round 8
// 132.302 us; speedup vs baseline: 1.0287x; 1.0287x over previous
//
#include <hip/hip_runtime.h>
#include <math.h>
#include <float.h>

#define BN 2
#define NP 1024
#define NC 81
#define NCLS 80           // NC-1 foreground classes
#define ND 100
#define NSLOT 64          // fixed survivor slots per (image,class)
#define CAP2 512          // general-path candidate cap
#define CAPT 512          // tail compacted-superset cap
#define NBIN 4096
#define RPB 13            // softmax rows per block (79 blocks cover 1024 rows)
#define SCORE_T 0.05f
#define NMS_T 0.5f
#define BBOX_CLIP 4.135166556742356f   // log(1000/16)
#define DONE_TAG 0x5A5A5A5A            // != 0xAAAAAAAA ws poison

typedef unsigned long long ull;

// Decode one box, identical op order everywhere so results are bit-equal across uses.
__device__ __forceinline__ void decode_box(
    const float* __restrict__ props, const float* __restrict__ regress,
    int b, int n, int c, float& x1, float& y1, float& x2, float& y2)
{
    const float* pr = props + ((size_t)b * NP + n) * 4;
    float p0 = pr[0], p1 = pr[1], p2 = pr[2], p3 = pr[3];
    float w  = p2 - p0 + 1.0f, h = p3 - p1 + 1.0f;
    float cx = p0 + 0.5f * w,  cy = p1 + 0.5f * h;
    const float* rl = regress + (((size_t)b * NP + n) * NC + c) * 4;
    float dx = rl[0] / 10.0f, dy = rl[1] / 10.0f;
    float dw = fminf(rl[2] / 5.0f, BBOX_CLIP);
    float dh = fminf(rl[3] / 5.0f, BBOX_CLIP);
    float pcx = dx * w + cx, pcy = dy * h + cy;
    float pw  = expf(dw) * w, ph = expf(dh) * h;
    x1 = pcx - 0.5f * pw; y1 = pcy - 0.5f * ph;
    x2 = pcx + 0.5f * pw - 1.0f; y2 = pcy + 0.5f * ph - 1.0f;
    x1 = fminf(fmaxf(x1, 0.f), 1023.f);
    y1 = fminf(fmaxf(y1, 0.f), 1023.f);
    x2 = fminf(fmaxf(x2, 0.f), 1023.f);
    y2 = fminf(fmaxf(y2, 0.f), 1023.f);
}

__device__ __forceinline__ void emit_slot(
    float* __restrict__ out, const float* __restrict__ props,
    const float* __restrict__ regress, int b, int d, ull key)
{
    float score = __uint_as_float((unsigned int)(key >> 32));
    float* ob = out + ((size_t)b * ND + d) * 4;
    float* os = out + (size_t)BN * ND * 4 + b * ND + d;
    float* ol = out + (size_t)BN * ND * 5 + b * ND + d;
    if (score > 0.f) {
        unsigned int f = 0xFFFFFFFFu - (unsigned int)(key & 0xFFFFFFFFu);
        int cls = f / NP, n = f % NP;
        float x1, y1, x2, y2;
        decode_box(props, regress, b, n, cls + 1, x1, y1, x2, y2);
        ob[0] = x1; ob[1] = y1; ob[2] = x2; ob[3] = y2;
        *os = score;
        *ol = (float)(cls + 1);
    } else {
        ob[0] = 0.f; ob[1] = 0.f; ob[2] = 0.f; ob[3] = 0.f;
        *os = 0.f;
        *ol = -1.f;
    }
}

__device__ __forceinline__ void bitonic_desc(ull* a, int len, int tid, int nthr)
{
    for (int k = 2; k <= len; k <<= 1) {
        for (int j = k >> 1; j > 0; j >>= 1) {
            for (int i = tid; i < len; i += nthr) {
                int ixj = i ^ j;
                if (ixj > i) {
                    bool desc = ((i & k) == 0);
                    ull x = a[i], y = a[ixj];
                    if (desc ? (x < y) : (x > y)) { a[i] = y; a[ixj] = x; }
                }
            }
            __syncthreads();
        }
    }
}

// ------- Single fused kernel: distributed softmax + spin + NMS + spin-tail top-100 -------
__global__ __launch_bounds__(256) void roihead_kernel(
    const float* __restrict__ logits, const float* __restrict__ regress,
    const float* __restrict__ props, int* __restrict__ sflags, int* __restrict__ nflags,
    float* __restrict__ probs_t, ull* __restrict__ g_key, float* __restrict__ out)
{
    const int tid  = threadIdx.x;
    const int l    = tid & 63;
    const int wave = tid >> 6;
    const int idx  = blockIdx.x;
    const int b    = idx / NCLS;
    const int cls  = idx % NCLS;
    const int c    = cls + 1;

    __shared__ union {
        struct {                                  // general NMS path: 16 KB
            ull   key[CAP2];
            float x1[CAP2], y1[CAP2], x2[CAP2], y2[CAP2], area[CAP2];
            int   keep[CAP2];
        } a;
        struct {                                  // tail phase: 20 KB
            int hist[NBIN];
            ull cbuf[CAPT];
        } t;
    } sm;
    __shared__ int s_cnt, s_app, s_bstar, s_cnt2;

    // ---- phase 0: distributed softmax — this block handles RPB rows of image b ----
    {
        int r0 = cls * RPB;
        int r1 = r0 + RPB; if (r1 > NP) r1 = NP;
        for (int r = r0 + tid; r < r1; r += 256) {       // one thread per row
            const float* row = logits + ((size_t)b * NP + r) * NC;
            float m = -FLT_MAX;
            for (int i = 0; i < NC; ++i) m = fmaxf(m, row[i]);
            float s = 0.f;
            for (int i = 0; i < NC; ++i) s += expf(row[i] - m);
            for (int c2 = 1; c2 < NC; ++c2)
                probs_t[((size_t)b * NCLS + (c2 - 1)) * NP + r] = expf(row[c2] - m) / s;
        }
    }
    __syncthreads();
    __threadfence();
    if (tid == 0) atomicExch(&sflags[idx], DONE_TAG);
    // spin until all 80 blocks of this image finished their softmax slice
    if (tid < NCLS) {
        int* fp = sflags + b * NCLS + tid;
        while (atomicAdd(fp, 0) != DONE_TAG) { }
    }
    __syncthreads();
    __threadfence();                                     // acquire

    // ---- phase 1: scan own class row (coalesced float4), compact candidates ----
    if (tid == 0) { s_cnt = 0; s_app = 0; }
    __syncthreads();
    const float* prow = probs_t + ((size_t)b * NCLS + cls) * NP;
    float4 v = ((const float4*)prow)[tid];
    #pragma unroll
    for (int q = 0; q < 4; ++q) {
        float p = (&v.x)[q];
        if (p > SCORE_T) {
            int k = atomicAdd(&s_cnt, 1);
            if (k < CAP2) {
                unsigned n = (unsigned)(tid * 4 + q);
                sm.a.key[k] = ((ull)__float_as_uint(p) << 32)
                            | (ull)(0xFFFFFFFFu - n);
            }
        }
    }
    __syncthreads();
    int M = s_cnt; if (M > CAP2) M = CAP2;
    ull* g_slot = g_key + (size_t)idx * NSLOT;

    // ---- phase 2: NMS ----
    if (M > 64) {
        // general path (rare): LDS bitonic + barriered NMS, 256 threads
        int Mp = 128; while (Mp < M) Mp <<= 1;
        for (int i = M + tid; i < Mp; i += 256) sm.a.key[i] = 0ull;
        __syncthreads();
        bitonic_desc(sm.a.key, Mp, tid, 256);
        for (int i = tid; i < M; i += 256) {
            int n = (int)(0xFFFFFFFFu - (unsigned)(sm.a.key[i] & 0xFFFFFFFFu));
            float x1, y1, x2, y2;
            decode_box(props, regress, b, n, c, x1, y1, x2, y2);
            sm.a.x1[i] = x1; sm.a.y1[i] = y1; sm.a.x2[i] = x2; sm.a.y2[i] = y2;
            sm.a.area[i] = (x2 - x1 + 1.f) * (y2 - y1 + 1.f);
            sm.a.keep[i] = 1;
        }
        __syncthreads();
        for (int i = 0; i < M; ++i) {
            if (sm.a.keep[i]) {
                float x1i = sm.a.x1[i], y1i = sm.a.y1[i];
                float x2i = sm.a.x2[i], y2i = sm.a.y2[i], ai = sm.a.area[i];
                for (int j = i + 1 + tid; j < M; j += 256) {
                    float lx = fmaxf(x1i, sm.a.x1[j]);
                    float ly = fmaxf(y1i, sm.a.y1[j]);
                    float rx = fminf(x2i, sm.a.x2[j]);
                    float ry = fminf(y2i, sm.a.y2[j]);
                    float wd = fmaxf(rx - lx + 1.f, 0.f);
                    float ht = fmaxf(ry - ly + 1.f, 0.f);
                    float inter = wd * ht;
                    float iou = inter / (ai + sm.a.area[j] - inter);
                    if (iou > NMS_T) sm.a.keep[j] = 0;
                }
            }
            __syncthreads();
        }
        for (int i = tid; i < M; i += 256) {
            if (sm.a.keep[i]) {
                int pos = atomicAdd(&s_app, 1);
                if (pos < NSLOT) {
                    ull key = sm.a.key[i];
                    unsigned n = 0xFFFFFFFFu - (unsigned)(key & 0xFFFFFFFFu);
                    unsigned f = (unsigned)cls * NP + n;
                    g_slot[pos] = (key & 0xFFFFFFFF00000000ull)
                                | (ull)(0xFFFFFFFFu - f);
                }
            }
        }
        __syncthreads();
        int st = s_app; if (st > NSLOT) st = NSLOT;
        for (int i = st + tid; i < NSLOT; i += 256) g_slot[i] = 0ull;
    } else {
        // fast path: whole NMS in wave-0 registers (proven R6/R7 network)
        if (wave == 0) {
            ull key = (l < M) ? sm.a.key[l] : 0ull;
            #pragma unroll
            for (int k = 2; k <= 64; k <<= 1) {
                #pragma unroll
                for (int j = k >> 1; j > 0; j >>= 1) {
                    ull p = __shfl_xor(key, j, 64);
                    bool lower = (l & j) == 0;
                    bool up    = (l & k) != 0;
                    ull mn = key < p ? key : p;
                    ull mx = key < p ? p : key;
                    key = (lower == up) ? mn : mx;
                }
            }
            float x1 = 0.f, y1 = 0.f, x2 = 0.f, y2 = 0.f, ar = 0.f;
            if (l < M) {
                int n = (int)(0xFFFFFFFFu - (unsigned)(key & 0xFFFFFFFFu));
                decode_box(props, regress, b, n, c, x1, y1, x2, y2);
                ar = (x2 - x1 + 1.f) * (y2 - y1 + 1.f);
            }
            ull keep = (M >= 64) ? ~0ull : ((1ull << M) - 1ull);
            for (int i = 0; i < M; ++i) {
                if ((keep >> i) & 1ull) {
                    float xi1 = __shfl(x1, i, 64), yi1 = __shfl(y1, i, 64);
                    float xi2 = __shfl(x2, i, 64), yi2 = __shfl(y2, i, 64);
                    float ari = __shfl(ar, i, 64);
                    float lx = fmaxf(xi1, x1), ly = fmaxf(yi1, y1);
                    float rx = fminf(xi2, x2), ry = fminf(yi2, y2);
                    float wd = fmaxf(rx - lx + 1.f, 0.f);
                    float ht = fmaxf(ry - ly + 1.f, 0.f);
                    float inter = wd * ht;
                    float iou = inter / (ari + ar - inter);
                    ull sup = __ballot(iou > NMS_T && l > i);
                    keep &= ~sup;
                }
            }
            ull vout = 0ull;
            if ((keep >> l) & 1ull) {
                unsigned n = 0xFFFFFFFFu - (unsigned)(key & 0xFFFFFFFFu);
                unsigned f = (unsigned)cls * NP + n;
                vout = (key & 0xFFFFFFFF00000000ull) | (ull)(0xFFFFFFFFu - f);
            }
            g_slot[l] = vout;    // all 64 slots written (zeros where no survivor)
        }
    }

    // ---- release: slots visible, then tag this class done ----
    __syncthreads();
    __threadfence();
    if (tid == 0) atomicExch(&nflags[idx], DONE_TAG);
    if (cls != 0) return;

    // ---- tail (cls==0 block per image): spin on 80 nflags, then top-100 ----
    if (tid < NCLS) {
        int* fp = nflags + b * NCLS + tid;
        while (atomicAdd(fp, 0) != DONE_TAG) { }
    }
    __syncthreads();
    __threadfence();                               // acquire

    const int K = NCLS * NSLOT;                    // 5120 fixed slots
    const ull* keys = g_key + (size_t)b * NCLS * NSLOT;

    for (int i = tid; i < NBIN; i += 256) sm.t.hist[i] = 0;
    if (tid == 0) s_cnt2 = 0;
    __syncthreads();
    for (int i = tid; i < K; i += 256) {
        ull key = keys[i];
        if (key) atomicAdd(&sm.t.hist[(int)(key >> 52)], 1);
    }
    __syncthreads();

    // boundary bin b*: wave 0, suffix scan over 4096 bins (64 groups x 64)
    if (tid < 64) {
        int gs = 0;
        for (int q = 0; q < 64; ++q) gs += sm.t.hist[l * 64 + q];
        int pre = gs;
        for (int off = 1; off < 64; off <<= 1) {
            int vv = __shfl_up(pre, off, 64);
            if (l >= off) pre += vv;
        }
        int total = __shfl(pre, 63, 64);
        int S = total - pre + gs;
        ull ball = __ballot(S >= ND);
        int gstar = ball ? (63 - __clzll((long long)ball)) : 0;
        int Sg = __shfl(S, gstar, 64);
        int Gg = __shfl(gs, gstar, 64);
        int A  = Sg - Gg;
        int h  = sm.t.hist[gstar * 64 + l];
        int pre2 = h;
        for (int off = 1; off < 64; off <<= 1) {
            int vv = __shfl_up(pre2, off, 64);
            if (l >= off) pre2 += vv;
        }
        int T = Gg - pre2 + h;
        ull ball2 = __ballot(A + T >= ND);
        int binin = ball2 ? (63 - __clzll((long long)ball2)) : 0;
        if (l == 0) s_bstar = gstar * 64 + binin;
    }
    __syncthreads();
    const int bstar = s_bstar;

    for (int i = tid; i < K; i += 256) {
        ull key = keys[i];
        if (key && (int)(key >> 52) >= bstar) {
            int p = atomicAdd(&s_cnt2, 1);
            if (p < CAPT) sm.t.cbuf[p] = key;
        }
    }
    __syncthreads();
    const int Tt = s_cnt2;

    if (Tt <= 256) {
        // zero-barrier register bitonic: 256 elems = 64 lanes x 4 regs, e = r*64 + l
        if (wave == 0) {
            ull key4[4];
            #pragma unroll
            for (int r = 0; r < 4; ++r) {
                int e = r * 64 + l;
                key4[r] = (e < Tt) ? sm.t.cbuf[e] : 0ull;
            }
            #pragma unroll
            for (int k = 2; k <= 256; k <<= 1) {
                #pragma unroll
                for (int j = k >> 1; j > 0; j >>= 1) {
                    if (j >= 64) {
                        int d = j >> 6;                       // 1 or 2: in-thread pairs
                        #pragma unroll
                        for (int r = 0; r < 4; ++r) {
                            if ((r & d) == 0) {
                                int e = r * 64 + l;
                                bool desc = ((e & k) == 0);
                                ull aa = key4[r], bb = key4[r | d];
                                if (desc ? (aa < bb) : (aa > bb)) {
                                    key4[r] = bb; key4[r | d] = aa;
                                }
                            }
                        }
                    } else {
                        #pragma unroll
                        for (int r = 0; r < 4; ++r) {
                            ull p = __shfl_xor(key4[r], j, 64);
                            int e = r * 64 + l;
                            bool desc = ((e & k) == 0);
                            bool low  = ((l & j) == 0);
                            ull mn = key4[r] < p ? key4[r] : p;
                            ull mx = key4[r] < p ? p : key4[r];
                            key4[r] = (low == desc) ? mx : mn;
                        }
                    }
                }
            }
            emit_slot(out, props, regress, b, l, key4[0]);
            if (l < ND - 64) emit_slot(out, props, regress, b, 64 + l, key4[1]);
        }
    } else if (Tt <= CAPT) {
        int Tp = 512;
        for (int i = Tt + tid; i < Tp; i += 256) sm.t.cbuf[i] = 0ull;
        __syncthreads();
        bitonic_desc(sm.t.cbuf, Tp, tid, 256);
        for (int d = tid; d < ND; d += 256)
            emit_slot(out, props, regress, b, d, sm.t.cbuf[d]);
    } else {
        // fallback (statistically unreachable): ND destructive argmax rounds
        ull* rk = sm.a.key;
        int* rp = sm.a.keep;
        ull* wkeys = g_key + (size_t)b * NCLS * NSLOT;
        for (int d = 0; d < ND; ++d) {
            ull bk = 0ull; int bp = -1;
            for (int t = tid; t < K; t += 256) {
                ull k2 = wkeys[t];
                if (k2 > bk) { bk = k2; bp = t; }
            }
            rk[tid] = bk; rp[tid] = bp;
            __syncthreads();
            for (int off = 128; off > 0; off >>= 1) {
                if (tid < off && rk[tid + off] > rk[tid]) {
                    rk[tid] = rk[tid + off]; rp[tid] = rp[tid + off];
                }
                __syncthreads();
            }
            if (tid == 0) {
                emit_slot(out, props, regress, b, d, rk[0]);
                if (rp[0] >= 0) wkeys[rp[0]] = 0ull;
            }
            __syncthreads();
        }
    }
}

extern "C" void kernel_launch(void* const* d_in, const int* in_sizes, int n_in,
                              void* d_out, int out_size, void* d_ws, size_t ws_size,
                              hipStream_t stream) {
    const float* logits  = (const float*)d_in[0];   // [B, N, C]
    const float* regress = (const float*)d_in[1];   // [B, N, C*4]
    const float* props   = (const float*)d_in[2];   // [B, N, 4]
    float* out = (float*)d_out;                     // boxes(800) | scores(200) | labels(200)

    // Workspace layout (no zero-init needed anywhere; poison 0xAA != DONE_TAG):
    //   [0      , 640   )  sflags  : BN*NCLS ints (softmax-done)
    //   [1024   , 1664  )  nflags  : BN*NCLS ints (nms-done)
    //   [4096   , 659456)  probs_t : BN*NCLS*NP floats (640 KB)
    //   [659456 , 741376)  g_key   : BN*NCLS*NSLOT u64 fixed survivor slots (80 KB)
    char* ws = (char*)d_ws;
    int*   sflags  = (int*)(ws);
    int*   nflags  = (int*)(ws + 1024);
    float* probs_t = (float*)(ws + 4096);
    ull*   g_key   = (ull*)(ws + 4096 + (size_t)BN * NCLS * NP * 4);

    hipLaunchKernelGGL(roihead_kernel, dim3(BN * NCLS), dim3(256), 0, stream,
                       logits, regress, props, sflags, nflags, probs_t, g_key, out);
}

// Round 9
// 98.860 us; speedup vs baseline: 1.3767x; 1.3383x over previous
//
#include <hip/hip_runtime.h>
#include <math.h>
#include <float.h>

#define BN 2
#define NP 1024
#define NC 81
#define NCLS 80           // NC-1 foreground classes
#define ND 100
#define NSLOT 64          // fixed survivor slots per (image,class)
#define CAP2 512          // general-path candidate cap
#define CAPT 512          // tail compacted-superset cap
#define NBIN 4096
#define SCORE_T 0.05f
#define NMS_T 0.5f
#define BBOX_CLIP 4.135166556742356f   // log(1000/16)

typedef unsigned long long ull;

// Decode one box, identical op order everywhere so results are bit-equal across uses.
__device__ __forceinline__ void decode_box(
    const float* __restrict__ props, const float* __restrict__ regress,
    int b, int n, int c, float& x1, float& y1, float& x2, float& y2)
{
    const float* pr = props + ((size_t)b * NP + n) * 4;
    float p0 = pr[0], p1 = pr[1], p2 = pr[2], p3 = pr[3];
    float w  = p2 - p0 + 1.0f, h = p3 - p1 + 1.0f;
    float cx = p0 + 0.5f * w,  cy = p1 + 0.5f * h;
    const float* rl = regress + (((size_t)b * NP + n) * NC + c) * 4;
    float dx = rl[0] / 10.0f, dy = rl[1] / 10.0f;
    float dw = fminf(rl[2] / 5.0f, BBOX_CLIP);
    float dh = fminf(rl[3] / 5.0f, BBOX_CLIP);
    float pcx = dx * w + cx, pcy = dy * h + cy;
    float pw  = expf(dw) * w, ph = expf(dh) * h;
    x1 = pcx - 0.5f * pw; y1 = pcy - 0.5f * ph;
    x2 = pcx + 0.5f * pw - 1.0f; y2 = pcy + 0.5f * ph - 1.0f;
    x1 = fminf(fmaxf(x1, 0.f), 1023.f);
    y1 = fminf(fmaxf(y1, 0.f), 1023.f);
    x2 = fminf(fmaxf(x2, 0.f), 1023.f);
    y2 = fminf(fmaxf(y2, 0.f), 1023.f);
}

__device__ __forceinline__ void emit_slot(
    float* __restrict__ out, const float* __restrict__ props,
    const float* __restrict__ regress, int b, int d, ull key)
{
    float score = __uint_as_float((unsigned int)(key >> 32));
    float* ob = out + ((size_t)b * ND + d) * 4;
    float* os = out + (size_t)BN * ND * 4 + b * ND + d;
    float* ol = out + (size_t)BN * ND * 5 + b * ND + d;
    if (score > 0.f) {
        unsigned int f = 0xFFFFFFFFu - (unsigned int)(key & 0xFFFFFFFFu);
        int cls = f / NP, n = f % NP;
        float x1, y1, x2, y2;
        decode_box(props, regress, b, n, cls + 1, x1, y1, x2, y2);
        ob[0] = x1; ob[1] = y1; ob[2] = x2; ob[3] = y2;
        *os = score;
        *ol = (float)(cls + 1);
    } else {
        ob[0] = 0.f; ob[1] = 0.f; ob[2] = 0.f; ob[3] = 0.f;
        *os = 0.f;
        *ol = -1.f;
    }
}

__device__ __forceinline__ void bitonic_desc(ull* a, int len, int tid, int nthr)
{
    for (int k = 2; k <= len; k <<= 1) {
        for (int j = k >> 1; j > 0; j >>= 1) {
            for (int i = tid; i < len; i += nthr) {
                int ixj = i ^ j;
                if (ixj > i) {
                    bool desc = ((i & k) == 0);
                    ull x = a[i], y = a[ixj];
                    if (desc ? (x < y) : (x > y)) { a[i] = y; a[ixj] = x; }
                }
            }
            __syncthreads();
        }
    }
}

// ---- Kernel A: per-(image,class) register softmax + scan + register NMS -> 64 slots ----
// No fences, no flags: the kernel boundary is the release. Every slot is written.
__global__ __launch_bounds__(256) void nms_kernel(
    const float* __restrict__ logits, const float* __restrict__ regress,
    const float* __restrict__ props, ull* __restrict__ g_key)
{
    const int tid  = threadIdx.x;
    const int l    = tid & 63;
    const int wave = tid >> 6;
    const int idx  = blockIdx.x;
    const int b    = idx / NCLS;
    const int cls  = idx % NCLS;
    const int c    = cls + 1;

    __shared__ struct {                           // general path scratch (~16.5 KB)
        ull   key[CAP2];
        float x1[CAP2], y1[CAP2], x2[CAP2], y2[CAP2], area[CAP2];
        int   keep[CAP2];
    } sm;
    __shared__ int s_cnt, s_app;

    if (tid == 0) { s_cnt = 0; s_app = 0; }
    __syncthreads();

    // ---- fused softmax + candidate scan: 4 rows/thread, row held in registers ----
    #pragma unroll 1
    for (int k = 0; k < 4; ++k) {
        int r = tid + k * 256;                    // proposal index n
        const float* row = logits + ((size_t)b * NP + r) * NC;
        float v[NC];
        #pragma unroll
        for (int i = 0; i < NC; ++i) v[i] = row[i];
        float m = -FLT_MAX;
        #pragma unroll
        for (int i = 0; i < NC; ++i) m = fmaxf(m, v[i]);
        float s = 0.f;
        #pragma unroll
        for (int i = 0; i < NC; ++i) s += expf(v[i] - m);
        float lc = row[c];                        // one extra load, L1-hit
        float p = expf(lc - m) / s;
        if (p > SCORE_T) {
            int kk = atomicAdd(&s_cnt, 1);
            if (kk < CAP2)
                sm.key[kk] = ((ull)__float_as_uint(p) << 32)
                           | (ull)(0xFFFFFFFFu - (unsigned)r);
        }
    }
    __syncthreads();
    int M = s_cnt; if (M > CAP2) M = CAP2;
    ull* g_slot = g_key + (size_t)idx * NSLOT;

    if (M > 64) {
        // general path (rare): LDS bitonic + barriered NMS, 256 threads
        int Mp = 128; while (Mp < M) Mp <<= 1;
        for (int i = M + tid; i < Mp; i += 256) sm.key[i] = 0ull;
        __syncthreads();
        bitonic_desc(sm.key, Mp, tid, 256);
        for (int i = tid; i < M; i += 256) {
            int n = (int)(0xFFFFFFFFu - (unsigned)(sm.key[i] & 0xFFFFFFFFu));
            float x1, y1, x2, y2;
            decode_box(props, regress, b, n, c, x1, y1, x2, y2);
            sm.x1[i] = x1; sm.y1[i] = y1; sm.x2[i] = x2; sm.y2[i] = y2;
            sm.area[i] = (x2 - x1 + 1.f) * (y2 - y1 + 1.f);
            sm.keep[i] = 1;
        }
        __syncthreads();
        for (int i = 0; i < M; ++i) {
            if (sm.keep[i]) {
                float x1i = sm.x1[i], y1i = sm.y1[i];
                float x2i = sm.x2[i], y2i = sm.y2[i], ai = sm.area[i];
                for (int j = i + 1 + tid; j < M; j += 256) {
                    float lx = fmaxf(x1i, sm.x1[j]);
                    float ly = fmaxf(y1i, sm.y1[j]);
                    float rx = fminf(x2i, sm.x2[j]);
                    float ry = fminf(y2i, sm.y2[j]);
                    float wd = fmaxf(rx - lx + 1.f, 0.f);
                    float ht = fmaxf(ry - ly + 1.f, 0.f);
                    float inter = wd * ht;
                    float iou = inter / (ai + sm.area[j] - inter);
                    if (iou > NMS_T) sm.keep[j] = 0;
                }
            }
            __syncthreads();
        }
        for (int i = tid; i < M; i += 256) {
            if (sm.keep[i]) {
                int pos = atomicAdd(&s_app, 1);
                if (pos < NSLOT) {
                    ull key = sm.key[i];
                    unsigned n = 0xFFFFFFFFu - (unsigned)(key & 0xFFFFFFFFu);
                    unsigned f = (unsigned)cls * NP + n;
                    g_slot[pos] = (key & 0xFFFFFFFF00000000ull)
                                | (ull)(0xFFFFFFFFu - f);
                }
            }
        }
        __syncthreads();
        int st = s_app; if (st > NSLOT) st = NSLOT;
        for (int i = st + tid; i < NSLOT; i += 256) g_slot[i] = 0ull;
    } else {
        // fast path: whole NMS in wave-0 registers (proven R6-R8 network); M==0 writes zeros
        if (wave == 0) {
            ull key = (l < M) ? sm.key[l] : 0ull;
            #pragma unroll
            for (int k = 2; k <= 64; k <<= 1) {
                #pragma unroll
                for (int j = k >> 1; j > 0; j >>= 1) {
                    ull p = __shfl_xor(key, j, 64);
                    bool lower = (l & j) == 0;
                    bool up    = (l & k) != 0;
                    ull mn = key < p ? key : p;
                    ull mx = key < p ? p : key;
                    key = (lower == up) ? mn : mx;
                }
            }
            float x1 = 0.f, y1 = 0.f, x2 = 0.f, y2 = 0.f, ar = 0.f;
            if (l < M) {
                int n = (int)(0xFFFFFFFFu - (unsigned)(key & 0xFFFFFFFFu));
                decode_box(props, regress, b, n, c, x1, y1, x2, y2);
                ar = (x2 - x1 + 1.f) * (y2 - y1 + 1.f);
            }
            ull keep = (M >= 64) ? ~0ull : ((1ull << M) - 1ull);
            for (int i = 0; i < M; ++i) {
                if ((keep >> i) & 1ull) {
                    float xi1 = __shfl(x1, i, 64), yi1 = __shfl(y1, i, 64);
                    float xi2 = __shfl(x2, i, 64), yi2 = __shfl(y2, i, 64);
                    float ari = __shfl(ar, i, 64);
                    float lx = fmaxf(xi1, x1), ly = fmaxf(yi1, y1);
                    float rx = fminf(xi2, x2), ry = fminf(yi2, y2);
                    float wd = fmaxf(rx - lx + 1.f, 0.f);
                    float ht = fmaxf(ry - ly + 1.f, 0.f);
                    float inter = wd * ht;
                    float iou = inter / (ari + ar - inter);
                    ull sup = __ballot(iou > NMS_T && l > i);
                    keep &= ~sup;
                }
            }
            ull vout = 0ull;
            if ((keep >> l) & 1ull) {
                unsigned n = 0xFFFFFFFFu - (unsigned)(key & 0xFFFFFFFFu);
                unsigned f = (unsigned)cls * NP + n;
                vout = (key & 0xFFFFFFFF00000000ull) | (ull)(0xFFFFFFFFu - f);
            }
            g_slot[l] = vout;    // all 64 slots written (zeros where no survivor)
        }
    }
}

// ---- Kernel B: per-image top-100 (histogram radix-select + register bitonic) ----
__global__ __launch_bounds__(256) void topk_kernel(
    ull* __restrict__ g_key, const float* __restrict__ props,
    const float* __restrict__ regress, float* __restrict__ out)
{
    const int b   = blockIdx.x;
    const int tid = threadIdx.x;
    const int l   = tid & 63;
    const int wave = tid >> 6;

    __shared__ int hist[NBIN];                 // 16 KB
    __shared__ ull cbuf[CAPT];                 // 4 KB
    __shared__ ull rk[256];
    __shared__ int rp[256];
    __shared__ int s_bstar, s_cnt2;

    const int K = NCLS * NSLOT;                // 5120 fixed slots
    ull* keys = g_key + (size_t)b * K;

    for (int i = tid; i < NBIN; i += 256) hist[i] = 0;
    if (tid == 0) s_cnt2 = 0;
    __syncthreads();
    for (int i = tid; i < K; i += 256) {
        ull key = keys[i];
        if (key) atomicAdd(&hist[(int)(key >> 52)], 1);
    }
    __syncthreads();

    // boundary bin b*: wave 0, suffix scan over 4096 bins (64 groups x 64)
    if (tid < 64) {
        int gs = 0;
        for (int q = 0; q < 64; ++q) gs += hist[l * 64 + q];
        int pre = gs;
        for (int off = 1; off < 64; off <<= 1) {
            int vv = __shfl_up(pre, off, 64);
            if (l >= off) pre += vv;
        }
        int total = __shfl(pre, 63, 64);
        int S = total - pre + gs;
        ull ball = __ballot(S >= ND);
        int gstar = ball ? (63 - __clzll((long long)ball)) : 0;
        int Sg = __shfl(S, gstar, 64);
        int Gg = __shfl(gs, gstar, 64);
        int A  = Sg - Gg;
        int h  = hist[gstar * 64 + l];
        int pre2 = h;
        for (int off = 1; off < 64; off <<= 1) {
            int vv = __shfl_up(pre2, off, 64);
            if (l >= off) pre2 += vv;
        }
        int T = Gg - pre2 + h;
        ull ball2 = __ballot(A + T >= ND);
        int binin = ball2 ? (63 - __clzll((long long)ball2)) : 0;
        if (l == 0) s_bstar = gstar * 64 + binin;
    }
    __syncthreads();
    const int bstar = s_bstar;

    for (int i = tid; i < K; i += 256) {
        ull key = keys[i];
        if (key && (int)(key >> 52) >= bstar) {
            int p = atomicAdd(&s_cnt2, 1);
            if (p < CAPT) cbuf[p] = key;
        }
    }
    __syncthreads();
    const int Tt = s_cnt2;

    if (Tt <= 256) {
        // zero-barrier register bitonic: 256 elems = 64 lanes x 4 regs, e = r*64 + l
        if (wave == 0) {
            ull key4[4];
            #pragma unroll
            for (int r = 0; r < 4; ++r) {
                int e = r * 64 + l;
                key4[r] = (e < Tt) ? cbuf[e] : 0ull;
            }
            #pragma unroll
            for (int k = 2; k <= 256; k <<= 1) {
                #pragma unroll
                for (int j = k >> 1; j > 0; j >>= 1) {
                    if (j >= 64) {
                        int d = j >> 6;                       // 1 or 2: in-thread pairs
                        #pragma unroll
                        for (int r = 0; r < 4; ++r) {
                            if ((r & d) == 0) {
                                int e = r * 64 + l;
                                bool desc = ((e & k) == 0);
                                ull aa = key4[r], bb = key4[r | d];
                                if (desc ? (aa < bb) : (aa > bb)) {
                                    key4[r] = bb; key4[r | d] = aa;
                                }
                            }
                        }
                    } else {
                        #pragma unroll
                        for (int r = 0; r < 4; ++r) {
                            ull p = __shfl_xor(key4[r], j, 64);
                            int e = r * 64 + l;
                            bool desc = ((e & k) == 0);
                            bool low  = ((l & j) == 0);
                            ull mn = key4[r] < p ? key4[r] : p;
                            ull mx = key4[r] < p ? p : key4[r];
                            key4[r] = (low == desc) ? mx : mn;
                        }
                    }
                }
            }
            emit_slot(out, props, regress, b, l, key4[0]);
            if (l < ND - 64) emit_slot(out, props, regress, b, 64 + l, key4[1]);
        }
    } else if (Tt <= CAPT) {
        int Tp = 512;
        for (int i = Tt + tid; i < Tp; i += 256) cbuf[i] = 0ull;
        __syncthreads();
        bitonic_desc(cbuf, Tp, tid, 256);
        for (int d = tid; d < ND; d += 256)
            emit_slot(out, props, regress, b, d, cbuf[d]);
    } else {
        // fallback (statistically unreachable): ND destructive argmax rounds
        for (int d = 0; d < ND; ++d) {
            ull bk = 0ull; int bp = -1;
            for (int t = tid; t < K; t += 256) {
                ull k2 = keys[t];
                if (k2 > bk) { bk = k2; bp = t; }
            }
            rk[tid] = bk; rp[tid] = bp;
            __syncthreads();
            for (int off = 128; off > 0; off >>= 1) {
                if (tid < off && rk[tid + off] > rk[tid]) {
                    rk[tid] = rk[tid + off]; rp[tid] = rp[tid + off];
                }
                __syncthreads();
            }
            if (tid == 0) {
                emit_slot(out, props, regress, b, d, rk[0]);
                if (rp[0] >= 0) keys[rp[0]] = 0ull;
            }
            __syncthreads();
        }
    }
}

extern "C" void kernel_launch(void* const* d_in, const int* in_sizes, int n_in,
                              void* d_out, int out_size, void* d_ws, size_t ws_size,
                              hipStream_t stream) {
    const float* logits  = (const float*)d_in[0];   // [B, N, C]
    const float* regress = (const float*)d_in[1];   // [B, N, C*4]
    const float* props   = (const float*)d_in[2];   // [B, N, 4]
    float* out = (float*)d_out;                     // boxes(800) | scores(200) | labels(200)

    // Workspace: g_key only — BN*NCLS*NSLOT u64 fixed slots (80 KB), every slot
    // written by kernel A each call (no init / no poison assumptions).
    ull* g_key = (ull*)d_ws;

    hipLaunchKernelGGL(nms_kernel, dim3(BN * NCLS), dim3(256), 0, stream,
                       logits, regress, props, g_key);
    hipLaunchKernelGGL(topk_kernel, dim3(BN), dim3(256), 0, stream,
                       g_key, props, regress, out);
}